// Round 13
// baseline (147.741 us; speedup 1.0000x reference)
//
#include <hip/hip_runtime.h>
#include <hip/hip_fp16.h>
#include <math.h>

// Problem constants (fixed by the reference)
#define BN_NODES 16384     // B*N
#define DIM 128            // D
#define HID 256            // H
#define TK 4096            // distance-table knots (nearest-neighbor)
#define TRANGE 32.0f
#define TSTEP (TRANGE / (float)TK)   // 1/128
#define TINV  ((float)TK / TRANGE)   // 128
#define LN_EPS 1e-5f
#define EPB 4096           // edges per binning block
#define NBINS 256          // 64-node bins
#define NPB 64             // nodes per bin
#define CAPB 2560          // staging capacity per bin (mean 2048, +11 sigma)

// prep role ranges (table now 128 blocks x 32 knots: 4x fewer W2 re-reads,
// 67MB -> 16.7MB of L2 traffic — the same byte-model lever as r11/r12)
#define PB_TABLE_END 128
#define PB_W3T_END   192
#define PB_W4T_END   224
#define PB_CONV_END  1248
#define PB_BIN_START 1248

typedef _Float16 f16x8 __attribute__((ext_vector_type(8)));
typedef __attribute__((ext_vector_type(4))) float f32x4;
typedef __attribute__((ext_vector_type(2))) float floatx2;
typedef __attribute__((ext_vector_type(8))) unsigned short ushort8v;

__device__ __forceinline__ unsigned short f2h(float f) {
    _Float16 h = (_Float16)f;          // v_cvt_f16_f32, RNE
    return *(unsigned short*)&h;
}
__device__ __forceinline__ unsigned char f2fp8(float f) {
    unsigned int p = __builtin_amdgcn_cvt_pk_fp8_f32(f, f, 0, false);
    return (unsigned char)(p & 0xFFu);
}

// 8-dim accumulate for one edge: q = 8 fp8 dims of h_col, tv = 8 fp8 table dims
__device__ __forceinline__ void acc8(uint2 q, uint2 tv, float* a) {
    floatx2 h01 = __builtin_amdgcn_cvt_pk_f32_fp8((int)q.x, false);
    floatx2 h23 = __builtin_amdgcn_cvt_pk_f32_fp8((int)q.x, true);
    floatx2 h45 = __builtin_amdgcn_cvt_pk_f32_fp8((int)q.y, false);
    floatx2 h67 = __builtin_amdgcn_cvt_pk_f32_fp8((int)q.y, true);
    floatx2 t01 = __builtin_amdgcn_cvt_pk_f32_fp8((int)tv.x, false);
    floatx2 t23 = __builtin_amdgcn_cvt_pk_f32_fp8((int)tv.x, true);
    floatx2 t45 = __builtin_amdgcn_cvt_pk_f32_fp8((int)tv.y, false);
    floatx2 t67 = __builtin_amdgcn_cvt_pk_f32_fp8((int)tv.y, true);
    a[0] = fmaf(h01[0], t01[0], a[0]);
    a[1] = fmaf(h01[1], t01[1], a[1]);
    a[2] = fmaf(h23[0], t23[0], a[2]);
    a[3] = fmaf(h23[1], t23[1], a[3]);
    a[4] = fmaf(h45[0], t45[0], a[4]);
    a[5] = fmaf(h45[1], t45[1], a[5]);
    a[6] = fmaf(h67[0], t67[0], a[6]);
    a[7] = fmaf(h67[1], t67[1], a[7]);
}

__device__ __forceinline__ void edge_one(const unsigned int* lrec, int idx, int dd,
        const unsigned char* __restrict__ xq,
        const unsigned char* __restrict__ Tb, float* a) {
    unsigned int r0 = lrec[idx];
    int c0 = (int)((r0 >> 12) & 0x3FFFu), k0 = (int)(r0 & 0xFFFu);
    uint2 q0 = *(const uint2*)&xq[c0 * DIM + dd];
    uint2 t0 = *(const uint2*)&Tb[k0 * DIM + dd];
    acc8(q0, t0, a);
}

// ---- prep LDS union (max role = table, 48 KB) -----------------------------
struct PTable { float a[32 * 256]; float part[32 * 128]; };   // 48 KB
struct PTp    { float s[32 * 33]; };                          // 4.2 KB
struct PBin   { int cnt[NBINS]; int pre[NBINS]; int gba[NBINS];
                int sc[256]; unsigned int rec[EPB]; };        // 19 KB
union PU { PTable table; PTp tp; PBin bin; };

// ---------------------------------------------------------------------------
// K1 "prep":
//   blocks 0..127     : fp8 table Tb[4096][128], 32 knots/block (W2 read once
//                       per block -> 16.7MB total, was 67MB at 8 knots/block)
//   128..191          : W3 -> w3t fp16 transpose
//   192..223          : W4 -> w4t fp16 transpose
//   224..1247         : h -> xh fp16 AND xq fp8-e4m3
//   1248..            : edge binning into 256 bins (row>>6), rec=(r&63)<<26|c<<12|k
__global__ __launch_bounds__(256) void prep_kernel(
        const float* __restrict__ W1, const float* __restrict__ b1,
        const float* __restrict__ W2, const float* __restrict__ b2,
        const float* __restrict__ W3, const float* __restrict__ W4,
        const float* __restrict__ h, const int* __restrict__ ei,
        const float* __restrict__ x,
        unsigned char* __restrict__ Tb, unsigned short* __restrict__ w3t,
        unsigned short* __restrict__ w4t, unsigned short* __restrict__ xh,
        unsigned char* __restrict__ xq, int* __restrict__ bin_cursor,
        unsigned int* __restrict__ staging, int nE) {
    __shared__ __align__(16) PU u;
    int bid = blockIdx.x, t = threadIdx.x;
    if (bid < PB_TABLE_END) {
        float* a    = u.table.a;      // [32][256]
        float* part = u.table.part;   // [32][128]
        int k0 = bid * 32;
        float w1 = W1[t], bb = b1[t];
#pragma unroll
        for (int k = 0; k < 32; ++k) {
            float dist = ((float)(k0 + k) + 0.5f) * TSTEP;   // cell center
            float z = dist * w1 + bb;
            a[k * 256 + t] = z / (1.0f + expf(-z));
        }
        __syncthreads();
        int hg = t >> 7, d = t & 127;
        float acc[32];
#pragma unroll
        for (int k = 0; k < 32; ++k) acc[k] = 0.f;
        for (int hh = 0; hh < 128; ++hh) {
            int hidx = hg * 128 + hh;
            float w = W2[hidx * DIM + d];
#pragma unroll
            for (int k = 0; k < 32; ++k) acc[k] += a[k * 256 + hidx] * w;
        }
        if (hg == 1) {
#pragma unroll
            for (int k = 0; k < 32; ++k) part[k * 128 + d] = acc[k];
        }
        __syncthreads();
        if (hg == 0) {
            float bd = b2[d];
#pragma unroll
            for (int k = 0; k < 32; ++k)
                Tb[(k0 + k) * DIM + d] = f2fp8(acc[k] + part[k * 128 + d] + bd);
        }
    } else if (bid < PB_W3T_END) {
        float* s = u.tp.s;   // [32][33]
        int tid = bid - PB_TABLE_END, tr = tid >> 3, tc = tid & 7;
        int lr = t >> 5, lc = t & 31;
#pragma unroll
        for (int rep = 0; rep < 4; ++rep) {
            int k = tr * 32 + rep * 8 + lr, n = tc * 32 + lc;
            s[lc * 33 + rep * 8 + lr] = W3[k * 256 + n];
        }
        __syncthreads();
#pragma unroll
        for (int rep = 0; rep < 4; ++rep) {
            int n = tc * 32 + rep * 8 + lr, k = tr * 32 + lc;
            w3t[n * 256 + k] = f2h(s[(rep * 8 + lr) * 33 + lc]);
        }
    } else if (bid < PB_W4T_END) {
        float* s = u.tp.s;
        int tid = bid - PB_W3T_END, tr = tid >> 2, tc = tid & 3;
        int lr = t >> 5, lc = t & 31;
#pragma unroll
        for (int rep = 0; rep < 4; ++rep) {
            int k = tr * 32 + rep * 8 + lr, n = tc * 32 + lc;
            s[lc * 33 + rep * 8 + lr] = W4[k * 128 + n];
        }
        __syncthreads();
#pragma unroll
        for (int rep = 0; rep < 4; ++rep) {
            int n = tc * 32 + rep * 8 + lr, k = tr * 32 + lc;
            w4t[n * 256 + k] = f2h(s[(rep * 8 + lr) * 33 + lc]);
        }
    } else if (bid < PB_CONV_END) {
        int i0 = (bid - PB_W4T_END) * 2048 + t * 8;
        float4 v0 = *(const float4*)&h[i0];
        float4 v1 = *(const float4*)&h[i0 + 4];
        ushort8v o;
        o[0] = f2h(v0.x); o[1] = f2h(v0.y); o[2] = f2h(v0.z); o[3] = f2h(v0.w);
        o[4] = f2h(v1.x); o[5] = f2h(v1.y); o[6] = f2h(v1.z); o[7] = f2h(v1.w);
        *(ushort8v*)&xh[i0] = o;
        unsigned int q0 = 0, q1 = 0;
        q0 = __builtin_amdgcn_cvt_pk_fp8_f32(v0.x, v0.y, q0, false);
        q0 = __builtin_amdgcn_cvt_pk_fp8_f32(v0.z, v0.w, q0, true);
        q1 = __builtin_amdgcn_cvt_pk_fp8_f32(v1.x, v1.y, q1, false);
        q1 = __builtin_amdgcn_cvt_pk_fp8_f32(v1.z, v1.w, q1, true);
        uint2 qq; qq.x = q0; qq.y = q1;
        *(uint2*)&xq[i0] = qq;
    } else {
        // ---- edge binning role, 256 threads, EPB=4096 edges, 256 bins
        int e0 = (bid - PB_BIN_START) * EPB;
        int m = min(EPB, nE - e0);
        if (m < 0) m = 0;
        u.bin.cnt[t] = 0;
        __syncthreads();
        unsigned int code[16];
        int rk[16], bn[16];
#pragma unroll
        for (int j = 0; j < 16; ++j) {
            int idx = j * 256 + t;
            rk[j] = -1; bn[j] = 0; code[j] = 0;
            if (idx < m) {
                int e = e0 + idx;
                int r = ei[e], c = ei[nE + e];
                code[j] = ((unsigned int)r << 14) | (unsigned int)c;   // 28 bits
                bn[j] = r >> 6;
                rk[j] = atomicAdd(&u.bin.cnt[bn[j]], 1);
            }
        }
        __syncthreads();
        int c1 = u.bin.cnt[t];
        u.bin.sc[t] = c1;
        __syncthreads();
        for (int off = 1; off < 256; off <<= 1) {
            int v = (t >= off) ? u.bin.sc[t - off] : 0;
            __syncthreads();
            u.bin.sc[t] += v;
            __syncthreads();
        }
        u.bin.pre[t] = u.bin.sc[t] - c1;
        u.bin.gba[t] = atomicAdd(&bin_cursor[t], c1);
        __syncthreads();
#pragma unroll
        for (int j = 0; j < 16; ++j)
            if (rk[j] >= 0) u.bin.rec[u.bin.pre[bn[j]] + rk[j]] = code[j];
        __syncthreads();
        for (int i = t; i < m; i += 256) {
            unsigned int cd = u.bin.rec[i];
            int b = (int)(cd >> 20);            // row >> 6
            int r = (int)(cd >> 14);
            int c = (int)(cd & 0x3FFFu);
            float dx = x[r * 3 + 0] - x[c * 3 + 0];
            float dy = x[r * 3 + 1] - x[c * 3 + 1];
            float dz = x[r * 3 + 2] - x[c * 3 + 2];
            float uu = sqrtf(dx * dx + dy * dy + dz * dz) * TINV;
            int k = min((int)uu, TK - 1);
            unsigned int o = ((unsigned int)(r & 63) << 26)
                           | ((unsigned int)c << 12) | (unsigned int)k;
            int off = u.bin.gba[b] + (i - u.bin.pre[b]);
            if (off < CAPB) staging[b * CAPB + off] = o;   // 11-sigma guard
        }
    }
}

// ---------------------------------------------------------------------------
// K2 "mega" (r12-proven, unchanged): 256 blocks x 512 threads, 64 nodes/block.
__global__ __launch_bounds__(512, 4) void mega_kernel(
        const unsigned int* __restrict__ staging, const int* __restrict__ bin_cursor,
        const unsigned char* __restrict__ Tb, const unsigned char* __restrict__ xq,
        const unsigned short* __restrict__ xh, const unsigned short* __restrict__ w3t,
        const float* __restrict__ b3, const float* __restrict__ gamma,
        const float* __restrict__ beta, const unsigned short* __restrict__ w4t,
        const float* __restrict__ b4, float* __restrict__ out) {
    // union region: lrec[2560] (10 KB, phases 0-2) / a_lds[64][264] (33.8 KB)
    __shared__ __align__(16) unsigned short uni[NPB * 264];   // 33.8 KB
    unsigned int* lrec = (unsigned int*)uni;
    __shared__ int cnt64[NPB];
    __shared__ int pref[NPB + 1];
    __shared__ int cur[NPB];
    __shared__ __align__(16) unsigned short aggh[NPB][136];   // 17.4 KB
    __shared__ float part_s[8][NPB], part_q[8][NPB];          // 4 KB
    __shared__ float tot_mu[NPB], tot_rs[NPB];

    int t = threadIdx.x;
    int bin = blockIdx.x;
    int n0 = bin * NPB;
    if (t < NPB) cnt64[t] = 0;
    __syncthreads();
    int total = min(bin_cursor[bin], CAPB);
    long base = (long)bin * CAPB;

    // ---- phase 0: count pass (records cached in registers; total<=2560)
    unsigned int sr[5];
    int have[5];
#pragma unroll
    for (int j = 0; j < 5; ++j) {
        int idx = t + j * 512;
        have[j] = (idx < total);
        sr[j] = 0;
        if (have[j]) {
            sr[j] = __builtin_nontemporal_load(&staging[base + idx]);
            atomicAdd(&cnt64[sr[j] >> 26], 1);
        }
    }
    __syncthreads();
    if (t < NPB) {
        int c = cnt64[t];
        int s = c;
#pragma unroll
        for (int off = 1; off < NPB; off <<= 1) {
            int v = __shfl_up(s, off, NPB);
            if (t >= off) s += v;
        }
        pref[t + 1] = s;
        cur[t] = s - c;
        if (t == 0) pref[0] = 0;
    }
    __syncthreads();

    // ---- phase 1: scatter into CSR order
#pragma unroll
    for (int j = 0; j < 5; ++j)
        if (have[j]) { int pos = atomicAdd(&cur[sr[j] >> 26], 1); lrec[pos] = sr[j]; }
    __syncthreads();

    int wid = t >> 6, lane = t & 63;

    // ---- phase 2: group (wid*4+g) owns nodes 2*gidx, 2*gidx+1 sequentially
    {
        int g = lane >> 4, l16 = lane & 15, dd = l16 * 8;
        int gidx = wid * 4 + g;                // 0..31
#pragma unroll
        for (int nn = 0; nn < 2; ++nn) {
            int node = gidx * 2 + nn;
            int off = pref[node], len = pref[node + 1] - off;
            float a[8] = {0.f,0.f,0.f,0.f,0.f,0.f,0.f,0.f};
            int i = 0;
            for (; i + 3 < len; i += 4) {
                unsigned int r0 = lrec[off + i];
                unsigned int r1 = lrec[off + i + 1];
                unsigned int r2 = lrec[off + i + 2];
                unsigned int r3 = lrec[off + i + 3];
                int c0 = (int)((r0 >> 12) & 0x3FFFu), k0 = (int)(r0 & 0xFFFu);
                int c1 = (int)((r1 >> 12) & 0x3FFFu), k1 = (int)(r1 & 0xFFFu);
                int c2 = (int)((r2 >> 12) & 0x3FFFu), k2 = (int)(r2 & 0xFFFu);
                int c3 = (int)((r3 >> 12) & 0x3FFFu), k3 = (int)(r3 & 0xFFFu);
                uint2 q0 = *(const uint2*)&xq[c0 * DIM + dd];
                uint2 t0 = *(const uint2*)&Tb[k0 * DIM + dd];
                uint2 q1 = *(const uint2*)&xq[c1 * DIM + dd];
                uint2 t1 = *(const uint2*)&Tb[k1 * DIM + dd];
                uint2 q2 = *(const uint2*)&xq[c2 * DIM + dd];
                uint2 t2 = *(const uint2*)&Tb[k2 * DIM + dd];
                uint2 q3 = *(const uint2*)&xq[c3 * DIM + dd];
                uint2 t3 = *(const uint2*)&Tb[k3 * DIM + dd];
                acc8(q0, t0, a);
                acc8(q1, t1, a);
                acc8(q2, t2, a);
                acc8(q3, t3, a);
            }
            for (; i < len; ++i)
                edge_one(lrec, off + i, dd, xq, Tb, a);
            float inv = 1.0f / (float)max(len, 1);
            ushort8v o;
#pragma unroll
            for (int r = 0; r < 8; ++r) o[r] = f2h(a[r] * inv);
            *(ushort8v*)&aggh[node][dd] = o;
        }
    }
    __syncthreads();

    // ---- phase 3: GEMM1: U[64,256] = [xh | aggh] @ W3; wave owns 32 cols,
    //      FOUR m-subtiles share each B-fragment load
    int wv = wid, q = lane >> 4, l15 = lane & 15;
    f32x4 acc[4][2];   // [m-subtile][nt]
#pragma unroll
    for (int ms = 0; ms < 4; ++ms)
#pragma unroll
        for (int nt = 0; nt < 2; ++nt) acc[ms][nt] = (f32x4){0.f, 0.f, 0.f, 0.f};
    for (int kc = 0; kc < 8; ++kc) {
        f16x8 av[4];
        if (kc < 4) {
#pragma unroll
            for (int ms = 0; ms < 4; ++ms)
                av[ms] = *(const f16x8*)&xh[(n0 + ms * 16 + l15) * DIM + kc * 32 + q * 8];
        } else {
#pragma unroll
            for (int ms = 0; ms < 4; ++ms)
                av[ms] = *(const f16x8*)&aggh[ms * 16 + l15][(kc - 4) * 32 + q * 8];
        }
#pragma unroll
        for (int nt = 0; nt < 2; ++nt) {
            f16x8 b = *(const f16x8*)&w3t[(wv * 32 + nt * 16 + l15) * 256 + kc * 32 + q * 8];
#pragma unroll
            for (int ms = 0; ms < 4; ++ms)
                acc[ms][nt] = __builtin_amdgcn_mfma_f32_16x16x32_f16(av[ms], b, acc[ms][nt], 0, 0, 0);
        }
    }

    // bias + LN stats (intra-16-lane shfl, then cross-wave LDS sum)
    float b3v[2], gv[2], bvv[2];
#pragma unroll
    for (int nt = 0; nt < 2; ++nt) {
        int col = wv * 32 + nt * 16 + l15;
        b3v[nt] = b3[col]; gv[nt] = gamma[col]; bvv[nt] = beta[col];
    }
#pragma unroll
    for (int ms = 0; ms < 4; ++ms) {
        float s_[4], q_[4];
#pragma unroll
        for (int reg = 0; reg < 4; ++reg) {
            float su = 0.f, sq = 0.f;
#pragma unroll
            for (int nt = 0; nt < 2; ++nt) {
                float v = acc[ms][nt][reg] + b3v[nt];
                acc[ms][nt][reg] = v;
                su += v; sq += v * v;
            }
            s_[reg] = su; q_[reg] = sq;
        }
#pragma unroll
        for (int off = 1; off < 16; off <<= 1) {
#pragma unroll
            for (int reg = 0; reg < 4; ++reg) {
                s_[reg] += __shfl_xor(s_[reg], off, 64);
                q_[reg] += __shfl_xor(q_[reg], off, 64);
            }
        }
        if (l15 == 0) {
#pragma unroll
            for (int reg = 0; reg < 4; ++reg) {
                int r = ms * 16 + q * 4 + reg;
                part_s[wv][r] = s_[reg];
                part_q[wv][r] = q_[reg];
            }
        }
    }
    __syncthreads();
    if (t < NPB) {
        float st = 0.f, qt = 0.f;
#pragma unroll
        for (int w = 0; w < 8; ++w) { st += part_s[w][t]; qt += part_q[w][t]; }
        float mu = st * (1.0f / 256.0f);
        float var = qt * (1.0f / 256.0f) - mu * mu;
        tot_mu[t] = mu;
        tot_rs[t] = rsqrtf(var + LN_EPS);
    }
    __syncthreads();

    // LN + SiLU -> fp16 act into a_lds (aliases lrec; lrec dead since gather)
    unsigned short (*a_lds)[264] = (unsigned short(*)[264])uni;
#pragma unroll
    for (int ms = 0; ms < 4; ++ms) {
#pragma unroll
        for (int reg = 0; reg < 4; ++reg) {
            int r = ms * 16 + q * 4 + reg;
            float mu = tot_mu[r], rs = tot_rs[r];
#pragma unroll
            for (int nt = 0; nt < 2; ++nt) {
                float un = (acc[ms][nt][reg] - mu) * rs * gv[nt] + bvv[nt];
                float act = un / (1.0f + expf(-un));
                a_lds[r][wv * 32 + nt * 16 + l15] = f2h(act);
            }
        }
    }
    __syncthreads();

    // GEMM2: out[64,128] = act @ W4; wave owns 16 cols, 4 m-subtiles per B-frag
    f32x4 acc2[4];
#pragma unroll
    for (int ms = 0; ms < 4; ++ms) acc2[ms] = (f32x4){0.f, 0.f, 0.f, 0.f};
    int col2 = wv * 16 + l15;
    for (int kc = 0; kc < 8; ++kc) {
        f16x8 b = *(const f16x8*)&w4t[col2 * 256 + kc * 32 + q * 8];
#pragma unroll
        for (int ms = 0; ms < 4; ++ms) {
            f16x8 a = *(const f16x8*)&a_lds[ms * 16 + l15][kc * 32 + q * 8];
            acc2[ms] = __builtin_amdgcn_mfma_f32_16x16x32_f16(a, b, acc2[ms], 0, 0, 0);
        }
    }
    float b4v = b4[col2];
#pragma unroll
    for (int ms = 0; ms < 4; ++ms) {
#pragma unroll
        for (int reg = 0; reg < 4; ++reg) {
            int node = n0 + ms * 16 + q * 4 + reg;
            __builtin_nontemporal_store(acc2[ms][reg] + b4v, &out[node * DIM + col2]);
        }
    }
}

// ---------------------------------------------------------------------------
extern "C" void kernel_launch(void* const* d_in, const int* in_sizes, int n_in,
                              void* d_out, int out_size, void* d_ws, size_t ws_size,
                              hipStream_t stream) {
    const float* x     = (const float*)d_in[0];
    const float* h     = (const float*)d_in[1];
    const int*   ei    = (const int*)d_in[2];
    const float* W1    = (const float*)d_in[4];
    const float* b1    = (const float*)d_in[5];
    const float* W2    = (const float*)d_in[6];
    const float* b2    = (const float*)d_in[7];
    const float* W3    = (const float*)d_in[8];
    const float* b3    = (const float*)d_in[9];
    const float* gamma = (const float*)d_in[10];
    const float* beta  = (const float*)d_in[11];
    const float* W4    = (const float*)d_in[12];
    const float* b4    = (const float*)d_in[13];
    float* out = (float*)d_out;
    int nE = in_sizes[2] / 2;

    char* ws = (char*)d_ws;
    unsigned char*  Tb   = (unsigned char*)ws;  ws += (size_t)TK * DIM;           // 512 KB (fp8)
    unsigned short* w3t  = (unsigned short*)ws; ws += (size_t)HID * HID * 2;      // 128 KB
    unsigned short* w4t  = (unsigned short*)ws; ws += (size_t)DIM * HID * 2;      // 64 KB
    unsigned short* xh   = (unsigned short*)ws; ws += (size_t)BN_NODES * DIM * 2; // 4 MB
    unsigned char*  xq   = (unsigned char*)ws;  ws += (size_t)BN_NODES * DIM;     // 2 MB
    int* bin_cursor = (int*)ws;                 ws += (size_t)NBINS * 4;          // 1 KB
    unsigned int* staging = (unsigned int*)ws;  ws += (size_t)NBINS * CAPB * 4;   // 2.6 MB

    int binBlocks = (nE + EPB - 1) / EPB;
    hipMemsetAsync(bin_cursor, 0, (size_t)NBINS * 4, stream);
    prep_kernel<<<PB_BIN_START + binBlocks, 256, 0, stream>>>(W1, b1, W2, b2, W3, W4,
                                                              h, ei, x, Tb, w3t, w4t,
                                                              xh, xq, bin_cursor,
                                                              staging, nE);
    mega_kernel<<<NBINS, 512, 0, stream>>>(staging, bin_cursor, Tb, xq, xh,
                                           w3t, b3, gamma, beta, w4t, b4, out);
}

// Round 14
// 140.412 us; speedup vs baseline: 1.0522x; 1.0522x over previous
//
#include <hip/hip_runtime.h>
#include <hip/hip_fp16.h>
#include <math.h>

// Problem constants (fixed by the reference)
#define BN_NODES 16384     // B*N
#define DIM 128            // D
#define HID 256            // H
#define TK 4096            // distance-table knots (nearest-neighbor)
#define TRANGE 32.0f
#define TSTEP (TRANGE / (float)TK)   // 1/128
#define TINV  ((float)TK / TRANGE)   // 128
#define LN_EPS 1e-5f
#define EPB 4096           // edges per binning block
#define NBINS 256          // 64-node bins
#define NPB 64             // nodes per bin
#define CAPB 2560          // staging capacity per bin (mean 2048, +11 sigma)

typedef _Float16 f16x8 __attribute__((ext_vector_type(8)));
typedef __attribute__((ext_vector_type(4))) float f32x4;
typedef __attribute__((ext_vector_type(2))) float floatx2;
typedef __attribute__((ext_vector_type(8))) unsigned short ushort8v;

__device__ __forceinline__ unsigned short f2h(float f) {
    _Float16 h = (_Float16)f;          // v_cvt_f16_f32, RNE
    return *(unsigned short*)&h;
}
__device__ __forceinline__ unsigned char f2fp8(float f) {
    unsigned int p = __builtin_amdgcn_cvt_pk_fp8_f32(f, f, 0, false);
    return (unsigned char)(p & 0xFFu);
}

// 8-dim accumulate for one edge: q = 8 fp8 dims of h_col, tv = 8 fp8 table dims
__device__ __forceinline__ void acc8(uint2 q, uint2 tv, float* a) {
    floatx2 h01 = __builtin_amdgcn_cvt_pk_f32_fp8((int)q.x, false);
    floatx2 h23 = __builtin_amdgcn_cvt_pk_f32_fp8((int)q.x, true);
    floatx2 h45 = __builtin_amdgcn_cvt_pk_f32_fp8((int)q.y, false);
    floatx2 h67 = __builtin_amdgcn_cvt_pk_f32_fp8((int)q.y, true);
    floatx2 t01 = __builtin_amdgcn_cvt_pk_f32_fp8((int)tv.x, false);
    floatx2 t23 = __builtin_amdgcn_cvt_pk_f32_fp8((int)tv.x, true);
    floatx2 t45 = __builtin_amdgcn_cvt_pk_f32_fp8((int)tv.y, false);
    floatx2 t67 = __builtin_amdgcn_cvt_pk_f32_fp8((int)tv.y, true);
    a[0] = fmaf(h01[0], t01[0], a[0]);
    a[1] = fmaf(h01[1], t01[1], a[1]);
    a[2] = fmaf(h23[0], t23[0], a[2]);
    a[3] = fmaf(h23[1], t23[1], a[3]);
    a[4] = fmaf(h45[0], t45[0], a[4]);
    a[5] = fmaf(h45[1], t45[1], a[5]);
    a[6] = fmaf(h67[0], t67[0], a[6]);
    a[7] = fmaf(h67[1], t67[1], a[7]);
}

__device__ __forceinline__ void edge_one(const unsigned int* lrec, int idx, int dd,
        const unsigned char* __restrict__ xq,
        const unsigned char* __restrict__ Tb, float* a) {
    unsigned int r0 = lrec[idx];
    int c0 = (int)((r0 >> 12) & 0x3FFFu), k0 = (int)(r0 & 0xFFFu);
    uint2 q0 = *(const uint2*)&xq[c0 * DIM + dd];
    uint2 t0 = *(const uint2*)&Tb[k0 * DIM + dd];
    acc8(q0, t0, a);
}

// ---- prep LDS union: one region shared by all roles (max = binning ~20 KB;
//      r12 had table smem + binning arrays ADDITIVE ~32 KB; r13's 48 KB table
//      collapsed occupancy to 8.9% — lesson: union, and keep the max small)
struct PTable { float a[8 * 256]; float part[8 * 128]; };     // 12 KB
struct PTp    { float s[32 * 33]; };                          // 4.2 KB
struct PBin   { int cnt[NBINS]; int pre[NBINS]; int gba[NBINS];
                int sc[256]; unsigned int rec[EPB]; };        // 20 KB
union PU { PTable table; PTp tp; PBin bin; };

// ---------------------------------------------------------------------------
// K1 "prep" (r12-proven roles; LDS unified to 20 KB):
//   blocks 0..511     : fp8 table Tb[4096][128], 8 knots/block
//   512..575          : W3 -> w3t fp16 transpose
//   576..607          : W4 -> w4t fp16 transpose
//   608..1631         : h -> xh fp16 AND xq fp8-e4m3
//   1632..            : edge binning into 256 bins (row>>6), rec=(r&63)<<26|c<<12|k
__global__ __launch_bounds__(256) void prep_kernel(
        const float* __restrict__ W1, const float* __restrict__ b1,
        const float* __restrict__ W2, const float* __restrict__ b2,
        const float* __restrict__ W3, const float* __restrict__ W4,
        const float* __restrict__ h, const int* __restrict__ ei,
        const float* __restrict__ x,
        unsigned char* __restrict__ Tb, unsigned short* __restrict__ w3t,
        unsigned short* __restrict__ w4t, unsigned short* __restrict__ xh,
        unsigned char* __restrict__ xq, int* __restrict__ bin_cursor,
        unsigned int* __restrict__ staging, int nE) {
    __shared__ __align__(16) PU u;
    int bid = blockIdx.x, t = threadIdx.x;
    if (bid < 512) {
        float* a    = u.table.a;      // [8][256]
        float* part = u.table.part;   // [8][128]
        int k0 = bid * 8;
        float w1 = W1[t], bb = b1[t];
#pragma unroll
        for (int k = 0; k < 8; ++k) {
            float dist = ((float)(k0 + k) + 0.5f) * TSTEP;   // cell center
            float z = dist * w1 + bb;
            a[k * 256 + t] = z / (1.0f + expf(-z));
        }
        __syncthreads();
        int hg = t >> 7, d = t & 127;
        float acc[8] = {0.f,0.f,0.f,0.f,0.f,0.f,0.f,0.f};
        for (int hh = 0; hh < 128; ++hh) {
            int hidx = hg * 128 + hh;
            float w = W2[hidx * DIM + d];
#pragma unroll
            for (int k = 0; k < 8; ++k) acc[k] += a[k * 256 + hidx] * w;
        }
        if (hg == 1) {
#pragma unroll
            for (int k = 0; k < 8; ++k) part[k * 128 + d] = acc[k];
        }
        __syncthreads();
        if (hg == 0) {
            float bd = b2[d];
#pragma unroll
            for (int k = 0; k < 8; ++k)
                Tb[(k0 + k) * DIM + d] = f2fp8(acc[k] + part[k * 128 + d] + bd);
        }
    } else if (bid < 576) {
        float* s = u.tp.s;   // [32][33]
        int tid = bid - 512, tr = tid >> 3, tc = tid & 7;
        int lr = t >> 5, lc = t & 31;
#pragma unroll
        for (int rep = 0; rep < 4; ++rep) {
            int k = tr * 32 + rep * 8 + lr, n = tc * 32 + lc;
            s[lc * 33 + rep * 8 + lr] = W3[k * 256 + n];
        }
        __syncthreads();
#pragma unroll
        for (int rep = 0; rep < 4; ++rep) {
            int n = tc * 32 + rep * 8 + lr, k = tr * 32 + lc;
            w3t[n * 256 + k] = f2h(s[(rep * 8 + lr) * 33 + lc]);
        }
    } else if (bid < 608) {
        float* s = u.tp.s;
        int tid = bid - 576, tr = tid >> 2, tc = tid & 3;
        int lr = t >> 5, lc = t & 31;
#pragma unroll
        for (int rep = 0; rep < 4; ++rep) {
            int k = tr * 32 + rep * 8 + lr, n = tc * 32 + lc;
            s[lc * 33 + rep * 8 + lr] = W4[k * 128 + n];
        }
        __syncthreads();
#pragma unroll
        for (int rep = 0; rep < 4; ++rep) {
            int n = tc * 32 + rep * 8 + lr, k = tr * 32 + lc;
            w4t[n * 256 + k] = f2h(s[(rep * 8 + lr) * 33 + lc]);
        }
    } else if (bid < 1632) {
        int i0 = (bid - 608) * 2048 + t * 8;
        float4 v0 = *(const float4*)&h[i0];
        float4 v1 = *(const float4*)&h[i0 + 4];
        ushort8v o;
        o[0] = f2h(v0.x); o[1] = f2h(v0.y); o[2] = f2h(v0.z); o[3] = f2h(v0.w);
        o[4] = f2h(v1.x); o[5] = f2h(v1.y); o[6] = f2h(v1.z); o[7] = f2h(v1.w);
        *(ushort8v*)&xh[i0] = o;
        unsigned int q0 = 0, q1 = 0;
        q0 = __builtin_amdgcn_cvt_pk_fp8_f32(v0.x, v0.y, q0, false);
        q0 = __builtin_amdgcn_cvt_pk_fp8_f32(v0.z, v0.w, q0, true);
        q1 = __builtin_amdgcn_cvt_pk_fp8_f32(v1.x, v1.y, q1, false);
        q1 = __builtin_amdgcn_cvt_pk_fp8_f32(v1.z, v1.w, q1, true);
        uint2 qq; qq.x = q0; qq.y = q1;
        *(uint2*)&xq[i0] = qq;
    } else {
        // ---- edge binning role, 256 threads, EPB=4096 edges, 256 bins
        int e0 = (bid - 1632) * EPB;
        int m = min(EPB, nE - e0);
        if (m < 0) m = 0;
        u.bin.cnt[t] = 0;
        __syncthreads();
        unsigned int code[16];
        int rk[16], bn[16];
#pragma unroll
        for (int j = 0; j < 16; ++j) {
            int idx = j * 256 + t;
            rk[j] = -1; bn[j] = 0; code[j] = 0;
            if (idx < m) {
                int e = e0 + idx;
                int r = ei[e], c = ei[nE + e];
                code[j] = ((unsigned int)r << 14) | (unsigned int)c;   // 28 bits
                bn[j] = r >> 6;
                rk[j] = atomicAdd(&u.bin.cnt[bn[j]], 1);
            }
        }
        __syncthreads();
        int c1 = u.bin.cnt[t];
        u.bin.sc[t] = c1;
        __syncthreads();
        for (int off = 1; off < 256; off <<= 1) {
            int v = (t >= off) ? u.bin.sc[t - off] : 0;
            __syncthreads();
            u.bin.sc[t] += v;
            __syncthreads();
        }
        u.bin.pre[t] = u.bin.sc[t] - c1;
        u.bin.gba[t] = atomicAdd(&bin_cursor[t], c1);
        __syncthreads();
#pragma unroll
        for (int j = 0; j < 16; ++j)
            if (rk[j] >= 0) u.bin.rec[u.bin.pre[bn[j]] + rk[j]] = code[j];
        __syncthreads();
        for (int i = t; i < m; i += 256) {
            unsigned int cd = u.bin.rec[i];
            int b = (int)(cd >> 20);            // row >> 6
            int r = (int)(cd >> 14);
            int c = (int)(cd & 0x3FFFu);
            float dx = x[r * 3 + 0] - x[c * 3 + 0];
            float dy = x[r * 3 + 1] - x[c * 3 + 1];
            float dz = x[r * 3 + 2] - x[c * 3 + 2];
            float uu = sqrtf(dx * dx + dy * dy + dz * dz) * TINV;
            int k = min((int)uu, TK - 1);
            unsigned int o = ((unsigned int)(r & 63) << 26)
                           | ((unsigned int)c << 12) | (unsigned int)k;
            int off = u.bin.gba[b] + (i - u.bin.pre[b]);
            if (off < CAPB) staging[b * CAPB + off] = o;   // 11-sigma guard
        }
    }
}

// ---------------------------------------------------------------------------
// K2 "mega" (r12-proven, unchanged): 256 blocks x 512 threads, 64 nodes/block.
__global__ __launch_bounds__(512, 4) void mega_kernel(
        const unsigned int* __restrict__ staging, const int* __restrict__ bin_cursor,
        const unsigned char* __restrict__ Tb, const unsigned char* __restrict__ xq,
        const unsigned short* __restrict__ xh, const unsigned short* __restrict__ w3t,
        const float* __restrict__ b3, const float* __restrict__ gamma,
        const float* __restrict__ beta, const unsigned short* __restrict__ w4t,
        const float* __restrict__ b4, float* __restrict__ out) {
    // union region: lrec[2560] (10 KB, phases 0-2) / a_lds[64][264] (33.8 KB)
    __shared__ __align__(16) unsigned short uni[NPB * 264];   // 33.8 KB
    unsigned int* lrec = (unsigned int*)uni;
    __shared__ int cnt64[NPB];
    __shared__ int pref[NPB + 1];
    __shared__ int cur[NPB];
    __shared__ __align__(16) unsigned short aggh[NPB][136];   // 17.4 KB
    __shared__ float part_s[8][NPB], part_q[8][NPB];          // 4 KB
    __shared__ float tot_mu[NPB], tot_rs[NPB];

    int t = threadIdx.x;
    int bin = blockIdx.x;
    int n0 = bin * NPB;
    if (t < NPB) cnt64[t] = 0;
    __syncthreads();
    int total = min(bin_cursor[bin], CAPB);
    long base = (long)bin * CAPB;

    // ---- phase 0: count pass (records cached in registers; total<=2560)
    unsigned int sr[5];
    int have[5];
#pragma unroll
    for (int j = 0; j < 5; ++j) {
        int idx = t + j * 512;
        have[j] = (idx < total);
        sr[j] = 0;
        if (have[j]) {
            sr[j] = __builtin_nontemporal_load(&staging[base + idx]);
            atomicAdd(&cnt64[sr[j] >> 26], 1);
        }
    }
    __syncthreads();
    if (t < NPB) {
        int c = cnt64[t];
        int s = c;
#pragma unroll
        for (int off = 1; off < NPB; off <<= 1) {
            int v = __shfl_up(s, off, NPB);
            if (t >= off) s += v;
        }
        pref[t + 1] = s;
        cur[t] = s - c;
        if (t == 0) pref[0] = 0;
    }
    __syncthreads();

    // ---- phase 1: scatter into CSR order
#pragma unroll
    for (int j = 0; j < 5; ++j)
        if (have[j]) { int pos = atomicAdd(&cur[sr[j] >> 26], 1); lrec[pos] = sr[j]; }
    __syncthreads();

    int wid = t >> 6, lane = t & 63;

    // ---- phase 2: group (wid*4+g) owns nodes 2*gidx, 2*gidx+1 sequentially
    {
        int g = lane >> 4, l16 = lane & 15, dd = l16 * 8;
        int gidx = wid * 4 + g;                // 0..31
#pragma unroll
        for (int nn = 0; nn < 2; ++nn) {
            int node = gidx * 2 + nn;
            int off = pref[node], len = pref[node + 1] - off;
            float a[8] = {0.f,0.f,0.f,0.f,0.f,0.f,0.f,0.f};
            int i = 0;
            for (; i + 3 < len; i += 4) {
                unsigned int r0 = lrec[off + i];
                unsigned int r1 = lrec[off + i + 1];
                unsigned int r2 = lrec[off + i + 2];
                unsigned int r3 = lrec[off + i + 3];
                int c0 = (int)((r0 >> 12) & 0x3FFFu), k0 = (int)(r0 & 0xFFFu);
                int c1 = (int)((r1 >> 12) & 0x3FFFu), k1 = (int)(r1 & 0xFFFu);
                int c2 = (int)((r2 >> 12) & 0x3FFFu), k2 = (int)(r2 & 0xFFFu);
                int c3 = (int)((r3 >> 12) & 0x3FFFu), k3 = (int)(r3 & 0xFFFu);
                uint2 q0 = *(const uint2*)&xq[c0 * DIM + dd];
                uint2 t0 = *(const uint2*)&Tb[k0 * DIM + dd];
                uint2 q1 = *(const uint2*)&xq[c1 * DIM + dd];
                uint2 t1 = *(const uint2*)&Tb[k1 * DIM + dd];
                uint2 q2 = *(const uint2*)&xq[c2 * DIM + dd];
                uint2 t2 = *(const uint2*)&Tb[k2 * DIM + dd];
                uint2 q3 = *(const uint2*)&xq[c3 * DIM + dd];
                uint2 t3 = *(const uint2*)&Tb[k3 * DIM + dd];
                acc8(q0, t0, a);
                acc8(q1, t1, a);
                acc8(q2, t2, a);
                acc8(q3, t3, a);
            }
            for (; i < len; ++i)
                edge_one(lrec, off + i, dd, xq, Tb, a);
            float inv = 1.0f / (float)max(len, 1);
            ushort8v o;
#pragma unroll
            for (int r = 0; r < 8; ++r) o[r] = f2h(a[r] * inv);
            *(ushort8v*)&aggh[node][dd] = o;
        }
    }
    __syncthreads();

    // ---- phase 3: GEMM1: U[64,256] = [xh | aggh] @ W3; wave owns 32 cols,
    //      FOUR m-subtiles share each B-fragment load
    int wv = wid, q = lane >> 4, l15 = lane & 15;
    f32x4 acc[4][2];   // [m-subtile][nt]
#pragma unroll
    for (int ms = 0; ms < 4; ++ms)
#pragma unroll
        for (int nt = 0; nt < 2; ++nt) acc[ms][nt] = (f32x4){0.f, 0.f, 0.f, 0.f};
    for (int kc = 0; kc < 8; ++kc) {
        f16x8 av[4];
        if (kc < 4) {
#pragma unroll
            for (int ms = 0; ms < 4; ++ms)
                av[ms] = *(const f16x8*)&xh[(n0 + ms * 16 + l15) * DIM + kc * 32 + q * 8];
        } else {
#pragma unroll
            for (int ms = 0; ms < 4; ++ms)
                av[ms] = *(const f16x8*)&aggh[ms * 16 + l15][(kc - 4) * 32 + q * 8];
        }
#pragma unroll
        for (int nt = 0; nt < 2; ++nt) {
            f16x8 b = *(const f16x8*)&w3t[(wv * 32 + nt * 16 + l15) * 256 + kc * 32 + q * 8];
#pragma unroll
            for (int ms = 0; ms < 4; ++ms)
                acc[ms][nt] = __builtin_amdgcn_mfma_f32_16x16x32_f16(av[ms], b, acc[ms][nt], 0, 0, 0);
        }
    }

    // bias + LN stats (intra-16-lane shfl, then cross-wave LDS sum)
    float b3v[2], gv[2], bvv[2];
#pragma unroll
    for (int nt = 0; nt < 2; ++nt) {
        int col = wv * 32 + nt * 16 + l15;
        b3v[nt] = b3[col]; gv[nt] = gamma[col]; bvv[nt] = beta[col];
    }
#pragma unroll
    for (int ms = 0; ms < 4; ++ms) {
        float s_[4], q_[4];
#pragma unroll
        for (int reg = 0; reg < 4; ++reg) {
            float su = 0.f, sq = 0.f;
#pragma unroll
            for (int nt = 0; nt < 2; ++nt) {
                float v = acc[ms][nt][reg] + b3v[nt];
                acc[ms][nt][reg] = v;
                su += v; sq += v * v;
            }
            s_[reg] = su; q_[reg] = sq;
        }
#pragma unroll
        for (int off = 1; off < 16; off <<= 1) {
#pragma unroll
            for (int reg = 0; reg < 4; ++reg) {
                s_[reg] += __shfl_xor(s_[reg], off, 64);
                q_[reg] += __shfl_xor(q_[reg], off, 64);
            }
        }
        if (l15 == 0) {
#pragma unroll
            for (int reg = 0; reg < 4; ++reg) {
                int r = ms * 16 + q * 4 + reg;
                part_s[wv][r] = s_[reg];
                part_q[wv][r] = q_[reg];
            }
        }
    }
    __syncthreads();
    if (t < NPB) {
        float st = 0.f, qt = 0.f;
#pragma unroll
        for (int w = 0; w < 8; ++w) { st += part_s[w][t]; qt += part_q[w][t]; }
        float mu = st * (1.0f / 256.0f);
        float var = qt * (1.0f / 256.0f) - mu * mu;
        tot_mu[t] = mu;
        tot_rs[t] = rsqrtf(var + LN_EPS);
    }
    __syncthreads();

    // LN + SiLU -> fp16 act into a_lds (aliases lrec; lrec dead since gather)
    unsigned short (*a_lds)[264] = (unsigned short(*)[264])uni;
#pragma unroll
    for (int ms = 0; ms < 4; ++ms) {
#pragma unroll
        for (int reg = 0; reg < 4; ++reg) {
            int r = ms * 16 + q * 4 + reg;
            float mu = tot_mu[r], rs = tot_rs[r];
#pragma unroll
            for (int nt = 0; nt < 2; ++nt) {
                float un = (acc[ms][nt][reg] - mu) * rs * gv[nt] + bvv[nt];
                float act = un / (1.0f + expf(-un));
                a_lds[r][wv * 32 + nt * 16 + l15] = f2h(act);
            }
        }
    }
    __syncthreads();

    // GEMM2: out[64,128] = act @ W4; wave owns 16 cols, 4 m-subtiles per B-frag
    f32x4 acc2[4];
#pragma unroll
    for (int ms = 0; ms < 4; ++ms) acc2[ms] = (f32x4){0.f, 0.f, 0.f, 0.f};
    int col2 = wv * 16 + l15;
    for (int kc = 0; kc < 8; ++kc) {
        f16x8 b = *(const f16x8*)&w4t[col2 * 256 + kc * 32 + q * 8];
#pragma unroll
        for (int ms = 0; ms < 4; ++ms) {
            f16x8 a = *(const f16x8*)&a_lds[ms * 16 + l15][kc * 32 + q * 8];
            acc2[ms] = __builtin_amdgcn_mfma_f32_16x16x32_f16(a, b, acc2[ms], 0, 0, 0);
        }
    }
    float b4v = b4[col2];
#pragma unroll
    for (int ms = 0; ms < 4; ++ms) {
#pragma unroll
        for (int reg = 0; reg < 4; ++reg) {
            int node = n0 + ms * 16 + q * 4 + reg;
            __builtin_nontemporal_store(acc2[ms][reg] + b4v, &out[node * DIM + col2]);
        }
    }
}

// ---------------------------------------------------------------------------
extern "C" void kernel_launch(void* const* d_in, const int* in_sizes, int n_in,
                              void* d_out, int out_size, void* d_ws, size_t ws_size,
                              hipStream_t stream) {
    const float* x     = (const float*)d_in[0];
    const float* h     = (const float*)d_in[1];
    const int*   ei    = (const int*)d_in[2];
    const float* W1    = (const float*)d_in[4];
    const float* b1    = (const float*)d_in[5];
    const float* W2    = (const float*)d_in[6];
    const float* b2    = (const float*)d_in[7];
    const float* W3    = (const float*)d_in[8];
    const float* b3    = (const float*)d_in[9];
    const float* gamma = (const float*)d_in[10];
    const float* beta  = (const float*)d_in[11];
    const float* W4    = (const float*)d_in[12];
    const float* b4    = (const float*)d_in[13];
    float* out = (float*)d_out;
    int nE = in_sizes[2] / 2;

    char* ws = (char*)d_ws;
    unsigned char*  Tb   = (unsigned char*)ws;  ws += (size_t)TK * DIM;           // 512 KB (fp8)
    unsigned short* w3t  = (unsigned short*)ws; ws += (size_t)HID * HID * 2;      // 128 KB
    unsigned short* w4t  = (unsigned short*)ws; ws += (size_t)DIM * HID * 2;      // 64 KB
    unsigned short* xh   = (unsigned short*)ws; ws += (size_t)BN_NODES * DIM * 2; // 4 MB
    unsigned char*  xq   = (unsigned char*)ws;  ws += (size_t)BN_NODES * DIM;     // 2 MB
    int* bin_cursor = (int*)ws;                 ws += (size_t)NBINS * 4;          // 1 KB
    unsigned int* staging = (unsigned int*)ws;  ws += (size_t)NBINS * CAPB * 4;   // 2.6 MB

    int binBlocks = (nE + EPB - 1) / EPB;
    hipMemsetAsync(bin_cursor, 0, (size_t)NBINS * 4, stream);
    prep_kernel<<<1632 + binBlocks, 256, 0, stream>>>(W1, b1, W2, b2, W3, W4, h, ei, x,
                                                      Tb, w3t, w4t, xh, xq,
                                                      bin_cursor, staging, nE);
    mega_kernel<<<NBINS, 512, 0, stream>>>(staging, bin_cursor, Tb, xq, xh,
                                           w3t, b3, gamma, beta, w4t, b4, out);
}